// Round 13
// baseline (1452.768 us; speedup 1.0000x reference)
//
#include <hip/hip_runtime.h>
#include <hip/hip_fp16.h>

#define SEQ 2048
#define DIM 512

typedef __attribute__((ext_vector_type(8))) short short8;
typedef __attribute__((ext_vector_type(4))) float f32x4;
typedef _Float16 h8 __attribute__((ext_vector_type(8)));
typedef _Float16 h4 __attribute__((ext_vector_type(4)));

#define MFMA16(a, b, c) __builtin_amdgcn_mfma_f32_16x16x32_f16((a), (b), (c), 0, 0, 0)

#define GLOAD_LDS16(g, l)                                                              \
    __builtin_amdgcn_global_load_lds(                                                  \
        (const __attribute__((address_space(1))) unsigned int*)(g),                    \
        (__attribute__((address_space(3))) unsigned int*)(l), 16, 0, 0)

// ===== WIDE engine (R9-verified): 256x128, BK=64, 3 bufs, counted vmcnt ====
// MODE 0: projQ  qh[16384,512] = xh @ Wq' (virtual K=1024 = [Wqh|Wql]) + bq
// MODE 1: projKV kh/vt = xh @ wkv (K=512; n0<512 -> K out, else V^T out)
template <int MODE>
__global__ __launch_bounds__(512, 1) void gemmw(
    const _Float16* __restrict__ A, const _Float16* __restrict__ B,
    const float* __restrict__ biasA, const float* __restrict__ biasB,
    _Float16* __restrict__ o0, _Float16* __restrict__ ovt) {
    extern __shared__ char sm[];     // 3 * 49152
    constexpr int T  = (MODE == 0) ? 16 : 8;
    constexpr int PA = 512;
    constexpr int PB = (MODE == 0) ? 1024 : 512;

    int tid = threadIdx.x, wid = tid >> 6, lane = tid & 63, r = lane & 15, g = lane >> 4;
    int wm = wid >> 1, wn = wid & 1;
    int m0 = blockIdx.x * 256, n0 = blockIdx.y * 128;

    const _Float16* Ab = A + (size_t)m0 * 512;
    const _Float16* Bb = B + (size_t)n0 * PB;

    const char* gA[4];
    const char* gB[2];
    int ldsA[4], ldsB[2];
#pragma unroll
    for (int j = 0; j < 4; ++j) {
        int ci = j * 512 + tid;
        int row = ci >> 3, cl = ci & 7;
        int col16 = cl ^ (row & 7);
        gA[j] = (const char*)Ab + (size_t)row * (PA * 2) + col16 * 16;
        ldsA[j] = ci * 16;
    }
#pragma unroll
    for (int j = 0; j < 2; ++j) {
        int ci = j * 512 + tid;
        int row = ci >> 3, cl = ci & 7;
        int col16 = cl ^ (row & 7);
        gB[j] = (const char*)Bb + (size_t)row * (PB * 2) + col16 * 16;
        ldsB[j] = ci * 16;
    }
    int offA[4][2], offB[4][2];
#pragma unroll
    for (int m = 0; m < 4; ++m) {
        int rowA = wm * 64 + m * 16 + r;
        int rowB = wn * 64 + m * 16 + r;
#pragma unroll
        for (int ks = 0; ks < 2; ++ks) {
            offA[m][ks] = rowA * 128 + (((ks * 4 + g) ^ (rowA & 7)) * 16);
            offB[m][ks] = rowB * 128 + (((ks * 4 + g) ^ (rowB & 7)) * 16);
        }
    }

    f32x4 acc[4][4];
#pragma unroll
    for (int m = 0; m < 4; ++m)
#pragma unroll
        for (int n = 0; n < 4; ++n) acc[m][n] = (f32x4)(0.0f);

    auto STG = [&](int t, int b) {
        int ka = (MODE == 0) ? ((t & 7) * 128) : (t * 128);
        int kb = t * 128;
        char* dA = sm + b * 49152;
        char* dB = sm + b * 49152 + 32768;
#pragma unroll
        for (int j = 0; j < 4; ++j) GLOAD_LDS16(gA[j] + ka, dA + ldsA[j]);
#pragma unroll
        for (int j = 0; j < 2; ++j) GLOAD_LDS16(gB[j] + kb, dB + ldsB[j]);
    };

    STG(0, 0);
    STG(1, 1);
    asm volatile("s_waitcnt vmcnt(6)" ::: "memory");
    __builtin_amdgcn_s_barrier();

#pragma unroll
    for (int t = 0; t < T; ++t) {
        const int buf = t % 3;
        if (t + 2 < T) STG(t + 2, (t + 2) % 3);
        const char* bA = sm + buf * 49152;
        const char* bB = sm + buf * 49152 + 32768;
        h8 af[4][2], bf[4][2];
#pragma unroll
        for (int m = 0; m < 4; ++m)
#pragma unroll
            for (int ks = 0; ks < 2; ++ks) {
                af[m][ks] = *(const h8*)(bA + offA[m][ks]);
                bf[m][ks] = *(const h8*)(bB + offB[m][ks]);
            }
        __builtin_amdgcn_s_setprio(1);
#pragma unroll
        for (int ks = 0; ks < 2; ++ks)
#pragma unroll
            for (int m = 0; m < 4; ++m)
#pragma unroll
                for (int n = 0; n < 4; ++n)
                    acc[m][n] = MFMA16(af[m][ks], bf[n][ks], acc[m][n]);
        __builtin_amdgcn_s_setprio(0);
        if (t + 2 < T) asm volatile("s_waitcnt vmcnt(6)" ::: "memory");
        else if (t + 1 < T) asm volatile("s_waitcnt vmcnt(0)" ::: "memory");
        if (t + 1 < T) __builtin_amdgcn_s_barrier();
    }

    if (MODE == 0) {
#pragma unroll
        for (int n = 0; n < 4; ++n) {
            int col = n0 + wn * 64 + n * 16 + r;
            float bi = biasA[col];
#pragma unroll
            for (int m = 0; m < 4; ++m) {
                int grow0 = m0 + wm * 64 + m * 16 + 4 * g;
                for (int reg = 0; reg < 4; ++reg)
                    o0[(size_t)(grow0 + reg) * 512 + col] =
                        (_Float16)(acc[m][n][reg] + bi);
            }
        }
    } else {
        int p = n0 >> 9, ncl = n0 & 511;
        if (p == 0) {
#pragma unroll
            for (int n = 0; n < 4; ++n) {
                int col = ncl + wn * 64 + n * 16 + r;
                float bi = biasA[col];
#pragma unroll
                for (int m = 0; m < 4; ++m) {
                    int grow0 = m0 + wm * 64 + m * 16 + 4 * g;
                    for (int reg = 0; reg < 4; ++reg)
                        o0[(size_t)(grow0 + reg) * 512 + col] =
                            (_Float16)(acc[m][n][reg] + bi);
                }
            }
        } else {
            // V^T via LDS transpose -> coalesced 128B-per-thread writes
            __syncthreads();
            _Float16* tt = (_Float16*)sm;    // [128 d][256 s], pitch 264 = 66KB
#pragma unroll
            for (int n = 0; n < 4; ++n) {
                int dloc = wn * 64 + n * 16 + r;
                float bi = biasB[ncl + dloc];
#pragma unroll
                for (int m = 0; m < 4; ++m) {
                    int sloc = wm * 64 + m * 16 + 4 * g;
                    h4 pv;
                    pv[0] = (_Float16)(acc[m][n][0] + bi);
                    pv[1] = (_Float16)(acc[m][n][1] + bi);
                    pv[2] = (_Float16)(acc[m][n][2] + bi);
                    pv[3] = (_Float16)(acc[m][n][3] + bi);
                    *(h4*)(&tt[dloc * 264 + sloc]) = pv;
                }
            }
            __syncthreads();
            int b = m0 >> 11, s0b = m0 & 2047;
            int drow = tid >> 2, part = tid & 3;
            const char* src = (const char*)(tt + drow * 264 + part * 64);
            char* dst = (char*)(ovt + (size_t)b * (512 * 2048) +
                                (size_t)(ncl + drow) * 2048 + s0b + part * 64);
#pragma unroll
            for (int j = 0; j < 8; ++j)
                *(short8*)(dst + j * 16) = *(const short8*)(src + j * 16);
        }
    }
}

// ===== NARROW engine (R8-verified): 128x128, BK=64, dbuf ===================
// MODE 1: qk + tile-softmax: P'[b][2048,2048] f16 = exp(S - m_tile); stats out
// MODE 2: pv: out = sum_t sc[t][row] * (P'_t @ V_t)  (per-round rescale)
template <int MODE>
__global__ __launch_bounds__(256) void gemmn(
    const _Float16* __restrict__ A, const _Float16* __restrict__ B,
    _Float16* __restrict__ ph, float* __restrict__ tmx, float* __restrict__ tsm,
    const float* __restrict__ scb, float* __restrict__ of, int bat0) {
    __shared__ char sm[2 * 32768];
    constexpr int T  = (MODE == 1) ? 8 : 32;
    constexpr int PA = (MODE == 1) ? 512 : 2048;
    constexpr int PB = (MODE == 1) ? 512 : 2048;

    int tid = threadIdx.x, wid = tid >> 6, lane = tid & 63, r = lane & 15, g = lane >> 4;
    int mw = wid >> 1, nw = wid & 1;
    int m0 = blockIdx.x * 128, n0 = blockIdx.y * 128, bz = blockIdx.z;

    const _Float16 *Ab, *Bb;
    if (MODE == 1) {
        int b = bat0 + bz;
        Ab = A + ((size_t)(b * SEQ) + m0) * 512;
        Bb = B + ((size_t)(b * SEQ) + n0) * 512;
    } else {
        int b = bat0 + bz;
        Ab = A + (size_t)bz * (SEQ * (size_t)SEQ) + (size_t)m0 * 2048;
        Bb = B + (size_t)b * (512 * SEQ) + (size_t)n0 * 2048;
    }

    const char* gA[4];
    const char* gB[4];
    int ldsw[4];
#pragma unroll
    for (int j = 0; j < 4; ++j) {
        int ci = (j * 4 + wid) * 64 + lane;
        int row = ci >> 3, cl = ci & 7;
        int col16 = cl ^ (row & 7);
        gA[j] = (const char*)Ab + (size_t)row * (PA * 2) + col16 * 16;
        gB[j] = (const char*)Bb + (size_t)row * (PB * 2) + col16 * 16;
        ldsw[j] = (j * 4 + wid) * 1024;
    }
    int offA[4][2], offB[4][2];
#pragma unroll
    for (int m = 0; m < 4; ++m) {
        int rowA = mw * 64 + m * 16 + r;
        int rowB = nw * 64 + m * 16 + r;
#pragma unroll
        for (int ks = 0; ks < 2; ++ks) {
            offA[m][ks] = rowA * 128 + (((ks * 4 + g) ^ (rowA & 7)) * 16);
            offB[m][ks] = rowB * 128 + (((ks * 4 + g) ^ (rowB & 7)) * 16);
        }
    }

    f32x4 acc[4][4];
#pragma unroll
    for (int m = 0; m < 4; ++m)
#pragma unroll
        for (int n = 0; n < 4; ++n) acc[m][n] = (f32x4)(0.0f);

    auto STG = [&](int t, int b) {
        int ka = t * 128, kb = t * 128;
        char* dA = sm + b * 32768;
        char* dB = sm + b * 32768 + 16384;
#pragma unroll
        for (int j = 0; j < 4; ++j) {
            GLOAD_LDS16(gA[j] + ka, dA + ldsw[j]);
            GLOAD_LDS16(gB[j] + kb, dB + ldsw[j]);
        }
    };

    STG(0, 0);
    asm volatile("s_waitcnt vmcnt(0)" ::: "memory");
    __builtin_amdgcn_s_barrier();

#pragma unroll
    for (int t = 0; t < T; ++t) {
        const int buf = t & 1;
        if (t + 1 < T) STG(t + 1, buf ^ 1);
        f32x4 s4[4];
        if constexpr (MODE == 2) {
            const float* sp = scb + (size_t)bz * (32 * SEQ) + (size_t)t * SEQ +
                              m0 + mw * 64 + 4 * g;
#pragma unroll
            for (int m = 0; m < 4; ++m) s4[m] = *(const f32x4*)(sp + m * 16);
        }
        const char* bA = sm + buf * 32768;
        const char* bB = sm + buf * 32768 + 16384;
        h8 af[4][2], bf[4][2];
#pragma unroll
        for (int m = 0; m < 4; ++m)
#pragma unroll
            for (int ks = 0; ks < 2; ++ks) {
                af[m][ks] = *(const h8*)(bA + offA[m][ks]);
                bf[m][ks] = *(const h8*)(bB + offB[m][ks]);
            }
        if constexpr (MODE == 1) {
#pragma unroll
            for (int ks = 0; ks < 2; ++ks)
#pragma unroll
                for (int m = 0; m < 4; ++m)
#pragma unroll
                    for (int n = 0; n < 4; ++n)
                        acc[m][n] = MFMA16(af[m][ks], bf[n][ks], acc[m][n]);
        } else {
            f32x4 acc2[4][4];
#pragma unroll
            for (int m = 0; m < 4; ++m)
#pragma unroll
                for (int n = 0; n < 4; ++n) acc2[m][n] = (f32x4)(0.0f);
#pragma unroll
            for (int ks = 0; ks < 2; ++ks)
#pragma unroll
                for (int m = 0; m < 4; ++m)
#pragma unroll
                    for (int n = 0; n < 4; ++n)
                        acc2[m][n] = MFMA16(af[m][ks], bf[n][ks], acc2[m][n]);
#pragma unroll
            for (int m = 0; m < 4; ++m)
#pragma unroll
                for (int n = 0; n < 4; ++n)
                    acc[m][n] += s4[m] * acc2[m][n];
        }
        if (t + 1 < T) {
            asm volatile("s_waitcnt vmcnt(0)" ::: "memory");
            __builtin_amdgcn_s_barrier();
        }
    }

    if constexpr (MODE == 1) {
        // tile-local softmax epilogue: 64-col tiles, rows in 16-lane groups
        _Float16* pb = ph + (size_t)bz * (SEQ * (size_t)SEQ);
        float* mxp = tmx + (size_t)bz * (32 * SEQ);
        float* smp = tsm + (size_t)bz * (32 * SEQ);
        int tileIdx = (n0 + nw * 64) >> 6;
#pragma unroll
        for (int m = 0; m < 4; ++m)
#pragma unroll
            for (int reg = 0; reg < 4; ++reg) {
                int row = m0 + mw * 64 + m * 16 + 4 * g + reg;
                float v0 = acc[m][0][reg], v1 = acc[m][1][reg];
                float v2 = acc[m][2][reg], v3 = acc[m][3][reg];
                float tm = fmaxf(fmaxf(v0, v1), fmaxf(v2, v3));
                for (int d = 1; d < 16; d <<= 1) tm = fmaxf(tm, __shfl_xor(tm, d));
                float p0 = __expf(v0 - tm), p1 = __expf(v1 - tm);
                float p2 = __expf(v2 - tm), p3 = __expf(v3 - tm);
                float s = (p0 + p1) + (p2 + p3);
                for (int d = 1; d < 16; d <<= 1) s += __shfl_xor(s, d);
                size_t rb = (size_t)row * SEQ + n0 + nw * 64;
                pb[rb + 0 * 16 + r] = (_Float16)p0;
                pb[rb + 1 * 16 + r] = (_Float16)p1;
                pb[rb + 2 * 16 + r] = (_Float16)p2;
                pb[rb + 3 * 16 + r] = (_Float16)p3;
                if (r == 0) {
                    mxp[tileIdx * SEQ + row] = tm;
                    smp[tileIdx * SEQ + row] = s;
                }
            }
    } else {
        int b = bat0 + bz;
#pragma unroll
        for (int n = 0; n < 4; ++n) {
            int col = n0 + nw * 64 + n * 16 + r;
#pragma unroll
            for (int m = 0; m < 4; ++m) {
                int grow0 = m0 + mw * 64 + m * 16 + 4 * g;
                for (int reg = 0; reg < 4; ++reg)
                    of[(size_t)(b * SEQ + grow0 + reg) * 512 + col] = acc[m][n][reg];
            }
        }
    }
}

// ---------------- k3lite: combine 32 tile-stats per row -> scales -----------
__global__ __launch_bounds__(256) void k3lite(
    const float* __restrict__ tmx, const float* __restrict__ tsm,
    float* __restrict__ sc) {
    int row = blockIdx.x * 256 + threadIdx.x;   // [0, nb*2048)
    int bz = row >> 11, rr = row & 2047;
    const float* mx = tmx + (size_t)bz * (32 * SEQ);
    const float* sp = tsm + (size_t)bz * (32 * SEQ);
    float* so = sc + (size_t)bz * (32 * SEQ);
    float mv[32];
    float m = -3.0e38f;
#pragma unroll
    for (int t = 0; t < 32; ++t) {
        mv[t] = mx[t * SEQ + rr];
        m = fmaxf(m, mv[t]);
    }
    float cv[32];
    float l = 0.0f;
#pragma unroll
    for (int t = 0; t < 32; ++t) {
        cv[t] = __expf(mv[t] - m);
        l += cv[t] * sp[t * SEQ + rr];
    }
    float inv = 1.0f / l;
#pragma unroll
    for (int t = 0; t < 32; ++t) so[t * SEQ + rr] = cv[t] * inv;
}

// ---------------- K0a: Wq -> hi|lo stacked (K=1024); Wk,Wv -> hi only -------
__global__ __launch_bounds__(256) void k0a_splitw(
    const float* __restrict__ Wq, const float* __restrict__ Wk, const float* __restrict__ Wv,
    _Float16* __restrict__ wq, _Float16* __restrict__ wkv) {
    int idx = blockIdx.x * 256 + threadIdx.x;   // [0, 3*512*512)
    int p = idx >> 18;
    int rem = idx & 262143;
    int k = rem >> 9, n = rem & 511;
    if (p == 0) {
        float w = Wq[rem];
        _Float16 h = (_Float16)w;
        wq[(size_t)n * 1024 + k] = h;
        wq[(size_t)n * 1024 + 512 + k] = (_Float16)(w - (float)h);
    } else if (p == 1) {
        wkv[(size_t)n * 512 + k] = (_Float16)Wk[rem];
    } else {
        wkv[(size_t)(512 + n) * 512 + k] = (_Float16)Wv[rem];
    }
}

// ---------------- K0b: x -> f16 ---------------------------------------------
__global__ __launch_bounds__(256) void k0b_splitx(
    const float* __restrict__ x, _Float16* __restrict__ xh) {
    size_t i = (size_t)(blockIdx.x * 256 + threadIdx.x) * 4;
    float4 v = *(const float4*)(x + i);
    h4 h;
    h[0] = (_Float16)v.x; h[1] = (_Float16)v.y;
    h[2] = (_Float16)v.z; h[3] = (_Float16)v.w;
    *(h4*)(xh + i) = h;
}

// ---------------------------------------------------------------------------
extern "C" void kernel_launch(void* const* d_in, const int* in_sizes, int n_in,
                              void* d_out, int out_size, void* d_ws, size_t ws_size,
                              hipStream_t stream) {
    const float* x  = (const float*)d_in[0];
    const float* Wq = (const float*)d_in[1];
    const float* bq = (const float*)d_in[2];
    const float* Wk = (const float*)d_in[3];
    const float* bk = (const float*)d_in[4];
    const float* Wv = (const float*)d_in[5];
    const float* bv = (const float*)d_in[6];
    float* out = (float*)d_out;

    char* ws = (char*)d_ws;
    const size_t QSZ = 16777216;   // 16384*512*2B
    _Float16* wq  = (_Float16*)(ws);                    // 1MB
    _Float16* wkv = (_Float16*)(ws + 1048576);          // 1MB
    _Float16* xh = (_Float16*)(ws + 3145728);
    _Float16* qh = (_Float16*)(ws + 3145728 + 1 * QSZ);
    _Float16* kh = (_Float16*)(ws + 3145728 + 2 * QSZ);
    _Float16* vt = (_Float16*)(ws + 3145728 + 3 * QSZ);
    const size_t sbase = 3145728 + 4 * QSZ;             // 70,254,592

    const int LDSW = 3 * 49152;   // 144 KB
    hipFuncSetAttribute((const void*)gemmw<0>,
                        hipFuncAttributeMaxDynamicSharedMemorySize, LDSW);
    hipFuncSetAttribute((const void*)gemmw<1>,
                        hipFuncAttributeMaxDynamicSharedMemorySize, LDSW);

    k0a_splitw<<<3072, 256, 0, stream>>>(Wq, Wk, Wv, wq, wkv);
    k0b_splitx<<<8192, 256, 0, stream>>>(x, xh);
    gemmw<0><<<dim3(64, 4), 512, LDSW, stream>>>(xh, wq, bq, nullptr, qh, nullptr);
    gemmw<1><<<dim3(64, 8), 512, LDSW, stream>>>(xh, wkv, bk, bv, kh, vt);

    // chunked attention: P' (8MB/batch f16) + 3 stat arrays (256KB/batch each)
    const size_t PSZ = (size_t)SEQ * SEQ * 2;        // 8 MB
    const size_t STF = 32 * SEQ;                      // floats per batch stat
    const size_t BSZ = PSZ + 3 * STF * 4;
    size_t avail = (ws_size > sbase) ? (ws_size - sbase) : 0;
    int chunk = (int)(avail / BSZ);
    if (chunk < 1) chunk = 1;
    if (chunk > 8) chunk = 8;
    _Float16* pbuf = (_Float16*)(ws + sbase);
    float* tmax = (float*)(ws + sbase + (size_t)chunk * PSZ);
    float* tsum = tmax + (size_t)chunk * STF;
    float* scb  = tsum + (size_t)chunk * STF;

    for (int b0 = 0; b0 < 8; b0 += chunk) {
        int nb = (8 - b0 < chunk) ? (8 - b0) : chunk;
        gemmn<1><<<dim3(16, 16, nb), 256, 0, stream>>>(qh, kh, pbuf, tmax, tsum,
                                                       nullptr, nullptr, b0);
        k3lite<<<dim3(nb * 8), 256, 0, stream>>>(tmax, tsum, scb);
        gemmn<2><<<dim3(16, 4, nb), 256, 0, stream>>>((const _Float16*)pbuf, vt,
                                                      nullptr, nullptr, nullptr,
                                                      scb, out, b0);
    }
}

// Round 14
// 176.591 us; speedup vs baseline: 8.2267x; 8.2267x over previous
//
#include <hip/hip_runtime.h>
#include <hip/hip_fp16.h>

#define SEQ 2048
#define DIM 512

typedef __attribute__((ext_vector_type(8))) short short8;
typedef __attribute__((ext_vector_type(4))) float f32x4;
typedef _Float16 h8 __attribute__((ext_vector_type(8)));
typedef _Float16 h4 __attribute__((ext_vector_type(4)));

#define MFMA16(a, b, c) __builtin_amdgcn_mfma_f32_16x16x32_f16((a), (b), (c), 0, 0, 0)

#define GLOAD_LDS16(g, l)                                                              \
    __builtin_amdgcn_global_load_lds(                                                  \
        (const __attribute__((address_space(1))) unsigned int*)(g),                    \
        (__attribute__((address_space(3))) unsigned int*)(l), 16, 0, 0)

// ===== WIDE engine (R9-verified): 256x128, BK=64, 3 bufs, counted vmcnt ====
// MODE 0: projQ  qh[16384,512] = xh @ Wq' (virtual K=1024 = [Wqh|Wql]) + bq
// MODE 1: projKV kh/vt = xh @ wkv (K=512; n0<512 -> K out, else V^T out)
template <int MODE>
__global__ __launch_bounds__(512, 1) void gemmw(
    const _Float16* __restrict__ A, const _Float16* __restrict__ B,
    const float* __restrict__ biasA, const float* __restrict__ biasB,
    _Float16* __restrict__ o0, _Float16* __restrict__ ovt) {
    extern __shared__ char sm[];     // 3 * 49152
    constexpr int T  = (MODE == 0) ? 16 : 8;
    constexpr int PA = 512;
    constexpr int PB = (MODE == 0) ? 1024 : 512;

    int tid = threadIdx.x, wid = tid >> 6, lane = tid & 63, r = lane & 15, g = lane >> 4;
    int wm = wid >> 1, wn = wid & 1;
    int m0 = blockIdx.x * 256, n0 = blockIdx.y * 128;

    const _Float16* Ab = A + (size_t)m0 * 512;
    const _Float16* Bb = B + (size_t)n0 * PB;

    const char* gA[4];
    const char* gB[2];
    int ldsA[4], ldsB[2];
#pragma unroll
    for (int j = 0; j < 4; ++j) {
        int ci = j * 512 + tid;
        int row = ci >> 3, cl = ci & 7;
        int col16 = cl ^ (row & 7);
        gA[j] = (const char*)Ab + (size_t)row * (PA * 2) + col16 * 16;
        ldsA[j] = ci * 16;
    }
#pragma unroll
    for (int j = 0; j < 2; ++j) {
        int ci = j * 512 + tid;
        int row = ci >> 3, cl = ci & 7;
        int col16 = cl ^ (row & 7);
        gB[j] = (const char*)Bb + (size_t)row * (PB * 2) + col16 * 16;
        ldsB[j] = ci * 16;
    }
    int offA[4][2], offB[4][2];
#pragma unroll
    for (int m = 0; m < 4; ++m) {
        int rowA = wm * 64 + m * 16 + r;
        int rowB = wn * 64 + m * 16 + r;
#pragma unroll
        for (int ks = 0; ks < 2; ++ks) {
            offA[m][ks] = rowA * 128 + (((ks * 4 + g) ^ (rowA & 7)) * 16);
            offB[m][ks] = rowB * 128 + (((ks * 4 + g) ^ (rowB & 7)) * 16);
        }
    }

    f32x4 acc[4][4];
#pragma unroll
    for (int m = 0; m < 4; ++m)
#pragma unroll
        for (int n = 0; n < 4; ++n) acc[m][n] = (f32x4)(0.0f);

    auto STG = [&](int t, int b) {
        int ka = (MODE == 0) ? ((t & 7) * 128) : (t * 128);
        int kb = t * 128;
        char* dA = sm + b * 49152;
        char* dB = sm + b * 49152 + 32768;
#pragma unroll
        for (int j = 0; j < 4; ++j) GLOAD_LDS16(gA[j] + ka, dA + ldsA[j]);
#pragma unroll
        for (int j = 0; j < 2; ++j) GLOAD_LDS16(gB[j] + kb, dB + ldsB[j]);
    };

    STG(0, 0);
    STG(1, 1);
    asm volatile("s_waitcnt vmcnt(6)" ::: "memory");
    __builtin_amdgcn_s_barrier();

#pragma unroll
    for (int t = 0; t < T; ++t) {
        const int buf = t % 3;
        if (t + 2 < T) STG(t + 2, (t + 2) % 3);
        const char* bA = sm + buf * 49152;
        const char* bB = sm + buf * 49152 + 32768;
        h8 af[4][2], bf[4][2];
#pragma unroll
        for (int m = 0; m < 4; ++m)
#pragma unroll
            for (int ks = 0; ks < 2; ++ks) {
                af[m][ks] = *(const h8*)(bA + offA[m][ks]);
                bf[m][ks] = *(const h8*)(bB + offB[m][ks]);
            }
        __builtin_amdgcn_s_setprio(1);
#pragma unroll
        for (int ks = 0; ks < 2; ++ks)
#pragma unroll
            for (int m = 0; m < 4; ++m)
#pragma unroll
                for (int n = 0; n < 4; ++n)
                    acc[m][n] = MFMA16(af[m][ks], bf[n][ks], acc[m][n]);
        __builtin_amdgcn_s_setprio(0);
        if (t + 2 < T) asm volatile("s_waitcnt vmcnt(6)" ::: "memory");
        else if (t + 1 < T) asm volatile("s_waitcnt vmcnt(0)" ::: "memory");
        if (t + 1 < T) __builtin_amdgcn_s_barrier();
    }

    if (MODE == 0) {
#pragma unroll
        for (int n = 0; n < 4; ++n) {
            int col = n0 + wn * 64 + n * 16 + r;
            float bi = biasA[col];
#pragma unroll
            for (int m = 0; m < 4; ++m) {
                int grow0 = m0 + wm * 64 + m * 16 + 4 * g;
                for (int reg = 0; reg < 4; ++reg)
                    o0[(size_t)(grow0 + reg) * 512 + col] =
                        (_Float16)(acc[m][n][reg] + bi);
            }
        }
    } else {
        int p = n0 >> 9, ncl = n0 & 511;
        if (p == 0) {
#pragma unroll
            for (int n = 0; n < 4; ++n) {
                int col = ncl + wn * 64 + n * 16 + r;
                float bi = biasA[col];
#pragma unroll
                for (int m = 0; m < 4; ++m) {
                    int grow0 = m0 + wm * 64 + m * 16 + 4 * g;
                    for (int reg = 0; reg < 4; ++reg)
                        o0[(size_t)(grow0 + reg) * 512 + col] =
                            (_Float16)(acc[m][n][reg] + bi);
                }
            }
        } else {
            // V^T via LDS transpose -> coalesced 128B-per-thread writes
            __syncthreads();
            _Float16* tt = (_Float16*)sm;    // [128 d][256 s], pitch 264 = 66KB
#pragma unroll
            for (int n = 0; n < 4; ++n) {
                int dloc = wn * 64 + n * 16 + r;
                float bi = biasB[ncl + dloc];
#pragma unroll
                for (int m = 0; m < 4; ++m) {
                    int sloc = wm * 64 + m * 16 + 4 * g;
                    h4 pv;
                    pv[0] = (_Float16)(acc[m][n][0] + bi);
                    pv[1] = (_Float16)(acc[m][n][1] + bi);
                    pv[2] = (_Float16)(acc[m][n][2] + bi);
                    pv[3] = (_Float16)(acc[m][n][3] + bi);
                    *(h4*)(&tt[dloc * 264 + sloc]) = pv;
                }
            }
            __syncthreads();
            int b = m0 >> 11, s0b = m0 & 2047;
            int drow = tid >> 2, part = tid & 3;
            const char* src = (const char*)(tt + drow * 264 + part * 64);
            char* dst = (char*)(ovt + (size_t)b * (512 * 2048) +
                                (size_t)(ncl + drow) * 2048 + s0b + part * 64);
#pragma unroll
            for (int j = 0; j < 8; ++j)
                *(short8*)(dst + j * 16) = *(const short8*)(src + j * 16);
        }
    }
}

// ===== NARROW engine (R8-verified): 128x128, BK=64, dbuf ===================
// MODE 1: qk + tile-softmax: P'[b][2048,2048] f16 = exp(S - m_tile); stats out
// MODE 2: pv: out = sum_t (sc[t][row] * P'_t) @ V_t  (scale folded into A)
template <int MODE>
__global__ __launch_bounds__(256) void gemmn(
    const _Float16* __restrict__ A, const _Float16* __restrict__ B,
    _Float16* __restrict__ ph, float* __restrict__ tmx, float* __restrict__ tsm,
    const float* __restrict__ scb, float* __restrict__ of, int bat0) {
    __shared__ char sm[2 * 32768];
    constexpr int T  = (MODE == 1) ? 8 : 32;
    constexpr int PA = (MODE == 1) ? 512 : 2048;
    constexpr int PB = (MODE == 1) ? 512 : 2048;

    int tid = threadIdx.x, wid = tid >> 6, lane = tid & 63, r = lane & 15, g = lane >> 4;
    int mw = wid >> 1, nw = wid & 1;
    int m0 = blockIdx.x * 128, n0 = blockIdx.y * 128, bz = blockIdx.z;

    const _Float16 *Ab, *Bb;
    if (MODE == 1) {
        int b = bat0 + bz;
        Ab = A + ((size_t)(b * SEQ) + m0) * 512;
        Bb = B + ((size_t)(b * SEQ) + n0) * 512;
    } else {
        int b = bat0 + bz;
        Ab = A + (size_t)bz * (SEQ * (size_t)SEQ) + (size_t)m0 * 2048;
        Bb = B + (size_t)b * (512 * SEQ) + (size_t)n0 * 2048;
    }

    const char* gA[4];
    const char* gB[4];
    int ldsw[4];
#pragma unroll
    for (int j = 0; j < 4; ++j) {
        int ci = (j * 4 + wid) * 64 + lane;
        int row = ci >> 3, cl = ci & 7;
        int col16 = cl ^ (row & 7);
        gA[j] = (const char*)Ab + (size_t)row * (PA * 2) + col16 * 16;
        gB[j] = (const char*)Bb + (size_t)row * (PB * 2) + col16 * 16;
        ldsw[j] = (j * 4 + wid) * 1024;
    }
    int offA[4][2], offB[4][2];
#pragma unroll
    for (int m = 0; m < 4; ++m) {
        int rowA = mw * 64 + m * 16 + r;
        int rowB = nw * 64 + m * 16 + r;
#pragma unroll
        for (int ks = 0; ks < 2; ++ks) {
            offA[m][ks] = rowA * 128 + (((ks * 4 + g) ^ (rowA & 7)) * 16);
            offB[m][ks] = rowB * 128 + (((ks * 4 + g) ^ (rowB & 7)) * 16);
        }
    }
    // per-lane scale base for MODE 2 (row = m0 + mw*64 + m*16 + r)
    const float* scp = nullptr;
    if constexpr (MODE == 2)
        scp = scb + (size_t)bz * (32 * SEQ) + m0 + mw * 64 + r;

    f32x4 acc[4][4];
#pragma unroll
    for (int m = 0; m < 4; ++m)
#pragma unroll
        for (int n = 0; n < 4; ++n) acc[m][n] = (f32x4)(0.0f);

    auto STG = [&](int t, int b) {
        int ka = t * 128, kb = t * 128;
        char* dA = sm + b * 32768;
        char* dB = sm + b * 32768 + 16384;
#pragma unroll
        for (int j = 0; j < 4; ++j) {
            GLOAD_LDS16(gA[j] + ka, dA + ldsw[j]);
            GLOAD_LDS16(gB[j] + kb, dB + ldsw[j]);
        }
    };

    STG(0, 0);
    asm volatile("s_waitcnt vmcnt(0)" ::: "memory");
    __builtin_amdgcn_s_barrier();

#pragma unroll
    for (int t = 0; t < T; ++t) {
        const int buf = t & 1;
        if (t + 1 < T) STG(t + 1, buf ^ 1);
        const char* bA = sm + buf * 32768;
        const char* bB = sm + buf * 32768 + 16384;
        h8 af[4][2], bf[4][2];
#pragma unroll
        for (int m = 0; m < 4; ++m)
#pragma unroll
            for (int ks = 0; ks < 2; ++ks) {
                af[m][ks] = *(const h8*)(bA + offA[m][ks]);
                bf[m][ks] = *(const h8*)(bB + offB[m][ks]);
            }
        if constexpr (MODE == 2) {
            // fold per-row scale into the P' fragments (A-operand linearity)
#pragma unroll
            for (int m = 0; m < 4; ++m) {
                _Float16 s = (_Float16)scp[(size_t)t * SEQ + m * 16];
#pragma unroll
                for (int ks = 0; ks < 2; ++ks)
#pragma unroll
                    for (int j = 0; j < 8; ++j) af[m][ks][j] *= s;
            }
        }
#pragma unroll
        for (int ks = 0; ks < 2; ++ks)
#pragma unroll
            for (int m = 0; m < 4; ++m)
#pragma unroll
                for (int n = 0; n < 4; ++n)
                    acc[m][n] = MFMA16(af[m][ks], bf[n][ks], acc[m][n]);
        if (t + 1 < T) {
            asm volatile("s_waitcnt vmcnt(0)" ::: "memory");
            __builtin_amdgcn_s_barrier();
        }
    }

    if constexpr (MODE == 1) {
        // tile-local softmax epilogue: 64-col tiles, rows in 16-lane groups
        _Float16* pb = ph + (size_t)bz * (SEQ * (size_t)SEQ);
        float* mxp = tmx + (size_t)bz * (32 * SEQ);
        float* smp = tsm + (size_t)bz * (32 * SEQ);
        int tileIdx = (n0 + nw * 64) >> 6;
#pragma unroll
        for (int m = 0; m < 4; ++m)
#pragma unroll
            for (int reg = 0; reg < 4; ++reg) {
                int row = m0 + mw * 64 + m * 16 + 4 * g + reg;
                float v0 = acc[m][0][reg], v1 = acc[m][1][reg];
                float v2 = acc[m][2][reg], v3 = acc[m][3][reg];
                float tm = fmaxf(fmaxf(v0, v1), fmaxf(v2, v3));
                for (int d = 1; d < 16; d <<= 1) tm = fmaxf(tm, __shfl_xor(tm, d));
                float p0 = __expf(v0 - tm), p1 = __expf(v1 - tm);
                float p2 = __expf(v2 - tm), p3 = __expf(v3 - tm);
                float s = (p0 + p1) + (p2 + p3);
                for (int d = 1; d < 16; d <<= 1) s += __shfl_xor(s, d);
                size_t rb = (size_t)row * SEQ + n0 + nw * 64;
                pb[rb + 0 * 16 + r] = (_Float16)p0;
                pb[rb + 1 * 16 + r] = (_Float16)p1;
                pb[rb + 2 * 16 + r] = (_Float16)p2;
                pb[rb + 3 * 16 + r] = (_Float16)p3;
                if (r == 0) {
                    mxp[tileIdx * SEQ + row] = tm;
                    smp[tileIdx * SEQ + row] = s;
                }
            }
    } else {
        int b = bat0 + bz;
#pragma unroll
        for (int n = 0; n < 4; ++n) {
            int col = n0 + nw * 64 + n * 16 + r;
#pragma unroll
            for (int m = 0; m < 4; ++m) {
                int grow0 = m0 + mw * 64 + m * 16 + 4 * g;
                for (int reg = 0; reg < 4; ++reg)
                    of[(size_t)(b * SEQ + grow0 + reg) * 512 + col] = acc[m][n][reg];
            }
        }
    }
}

// ---------------- k3lite: combine 32 tile-stats per row -> scales -----------
__global__ __launch_bounds__(256) void k3lite(
    const float* __restrict__ tmx, const float* __restrict__ tsm,
    float* __restrict__ sc) {
    int row = blockIdx.x * 256 + threadIdx.x;   // [0, nb*2048)
    int bz = row >> 11, rr = row & 2047;
    const float* mx = tmx + (size_t)bz * (32 * SEQ);
    const float* sp = tsm + (size_t)bz * (32 * SEQ);
    float* so = sc + (size_t)bz * (32 * SEQ);
    float mv[32];
    float m = -3.0e38f;
#pragma unroll
    for (int t = 0; t < 32; ++t) {
        mv[t] = mx[t * SEQ + rr];
        m = fmaxf(m, mv[t]);
    }
    float cv[32];
    float l = 0.0f;
#pragma unroll
    for (int t = 0; t < 32; ++t) {
        cv[t] = __expf(mv[t] - m);
        l += cv[t] * sp[t * SEQ + rr];
    }
    float inv = 1.0f / l;
#pragma unroll
    for (int t = 0; t < 32; ++t) so[t * SEQ + rr] = cv[t] * inv;
}

// ---------------- K0a: Wq -> hi|lo stacked (K=1024); Wk,Wv -> hi only -------
__global__ __launch_bounds__(256) void k0a_splitw(
    const float* __restrict__ Wq, const float* __restrict__ Wk, const float* __restrict__ Wv,
    _Float16* __restrict__ wq, _Float16* __restrict__ wkv) {
    int idx = blockIdx.x * 256 + threadIdx.x;   // [0, 3*512*512)
    int p = idx >> 18;
    int rem = idx & 262143;
    int k = rem >> 9, n = rem & 511;
    if (p == 0) {
        float w = Wq[rem];
        _Float16 h = (_Float16)w;
        wq[(size_t)n * 1024 + k] = h;
        wq[(size_t)n * 1024 + 512 + k] = (_Float16)(w - (float)h);
    } else if (p == 1) {
        wkv[(size_t)n * 512 + k] = (_Float16)Wk[rem];
    } else {
        wkv[(size_t)(512 + n) * 512 + k] = (_Float16)Wv[rem];
    }
}

// ---------------- K0b: x -> f16 ---------------------------------------------
__global__ __launch_bounds__(256) void k0b_splitx(
    const float* __restrict__ x, _Float16* __restrict__ xh) {
    size_t i = (size_t)(blockIdx.x * 256 + threadIdx.x) * 4;
    float4 v = *(const float4*)(x + i);
    h4 h;
    h[0] = (_Float16)v.x; h[1] = (_Float16)v.y;
    h[2] = (_Float16)v.z; h[3] = (_Float16)v.w;
    *(h4*)(xh + i) = h;
}

// ---------------------------------------------------------------------------
extern "C" void kernel_launch(void* const* d_in, const int* in_sizes, int n_in,
                              void* d_out, int out_size, void* d_ws, size_t ws_size,
                              hipStream_t stream) {
    const float* x  = (const float*)d_in[0];
    const float* Wq = (const float*)d_in[1];
    const float* bq = (const float*)d_in[2];
    const float* Wk = (const float*)d_in[3];
    const float* bk = (const float*)d_in[4];
    const float* Wv = (const float*)d_in[5];
    const float* bv = (const float*)d_in[6];
    float* out = (float*)d_out;

    char* ws = (char*)d_ws;
    const size_t QSZ = 16777216;   // 16384*512*2B
    _Float16* wq  = (_Float16*)(ws);                    // 1MB
    _Float16* wkv = (_Float16*)(ws + 1048576);          // 1MB
    _Float16* xh = (_Float16*)(ws + 3145728);
    _Float16* qh = (_Float16*)(ws + 3145728 + 1 * QSZ);
    _Float16* kh = (_Float16*)(ws + 3145728 + 2 * QSZ);
    _Float16* vt = (_Float16*)(ws + 3145728 + 3 * QSZ);
    const size_t sbase = 3145728 + 4 * QSZ;             // 70,254,592

    const int LDSW = 3 * 49152;   // 144 KB
    hipFuncSetAttribute((const void*)gemmw<0>,
                        hipFuncAttributeMaxDynamicSharedMemorySize, LDSW);
    hipFuncSetAttribute((const void*)gemmw<1>,
                        hipFuncAttributeMaxDynamicSharedMemorySize, LDSW);

    k0a_splitw<<<3072, 256, 0, stream>>>(Wq, Wk, Wv, wq, wkv);
    k0b_splitx<<<8192, 256, 0, stream>>>(x, xh);
    gemmw<0><<<dim3(64, 4), 512, LDSW, stream>>>(xh, wq, bq, nullptr, qh, nullptr);
    gemmw<1><<<dim3(64, 8), 512, LDSW, stream>>>(xh, wkv, bk, bv, kh, vt);

    // chunked attention: P' (8MB/batch f16) + 3 stat arrays (256KB/batch each)
    const size_t PSZ = (size_t)SEQ * SEQ * 2;        // 8 MB
    const size_t STF = 32 * SEQ;                      // floats per batch stat
    const size_t BSZ = PSZ + 3 * STF * 4;
    size_t avail = (ws_size > sbase) ? (ws_size - sbase) : 0;
    int chunk = (int)(avail / BSZ);
    if (chunk < 1) chunk = 1;
    if (chunk > 8) chunk = 8;
    _Float16* pbuf = (_Float16*)(ws + sbase);
    float* tmax = (float*)(ws + sbase + (size_t)chunk * PSZ);
    float* tsum = tmax + (size_t)chunk * STF;
    float* scb  = tsum + (size_t)chunk * STF;

    for (int b0 = 0; b0 < 8; b0 += chunk) {
        int nb = (8 - b0 < chunk) ? (8 - b0) : chunk;
        gemmn<1><<<dim3(16, 16, nb), 256, 0, stream>>>(qh, kh, pbuf, tmax, tsum,
                                                       nullptr, nullptr, b0);
        k3lite<<<dim3(nb * 8), 256, 0, stream>>>(tmax, tsum, scb);
        gemmn<2><<<dim3(16, 4, nb), 256, 0, stream>>>((const _Float16*)pbuf, vt,
                                                      nullptr, nullptr, nullptr,
                                                      scb, out, b0);
    }
}